// Round 8
// baseline (108.820 us; speedup 1.0000x reference)
//
#include <hip/hip_runtime.h>

// Problem constants: B=128, N=64, D=64
// Outputs (flat): kappa [B,N,N]=524288, diff [B,N,N,D]=33554432,
//                 gamma [B,1,1,1]=128, kappa_grad [B,N,N,D]=33554432
//
//  k1 (128 blocks):  per-batch dist^2 in regs -> exact lower median -> gamma,
//                    kappa = exp(-g*d2) via LDS, PLAIN coalesced stores
//                    (stays L2-resident for k2), m0 = -2*gamma -> d_ws.
//  k2 (2048 blocks): fill-shaped streaming. Two sequential grid-stride loops,
//                    each a single contiguous write stream:
//                      loop 1: diff  (134 MB)
//                      loop 2: kgrad (134 MB), kap/m0 reads L2-hot.

#define NBATCH 128

__global__ __launch_bounds__(256) void rbf_k1(
    const float* __restrict__ in1, const float* __restrict__ in2,
    float* __restrict__ out_gamma, float* __restrict__ out_kappa,
    float* __restrict__ m0tab)
{
    __shared__ float smem[2 * 64 * 64];   // A^T,B^T -> hist -> kappa
    __shared__ int   sWave[4];
    __shared__ int   sSel[2];
    __shared__ float sGamma;

    const int p    = blockIdx.x;
    const int t    = threadIdx.x;
    const int wave = t >> 6;
    const int lane = t & 63;

    float* sAT = smem;            // [d][i], stride 64
    float* sBT = smem + 4096;     // [d][j], stride 64

    const float* A  = in1 + p * 4096;
    const float* Bv = in2 + p * 4096;

    for (int e = t; e < 1024; e += 256) {
        int i = e >> 4, d0 = (e & 15) << 2;
        float4 av = *reinterpret_cast<const float4*>(A  + (i << 6) + d0);
        float4 bv = *reinterpret_cast<const float4*>(Bv + (i << 6) + d0);
        sAT[(d0+0)*64 + i] = av.x; sAT[(d0+1)*64 + i] = av.y;
        sAT[(d0+2)*64 + i] = av.z; sAT[(d0+3)*64 + i] = av.w;
        sBT[(d0+0)*64 + i] = bv.x; sBT[(d0+1)*64 + i] = bv.y;
        sBT[(d0+2)*64 + i] = bv.z; sBT[(d0+3)*64 + i] = bv.w;
    }
    __syncthreads();

    // 4x4 register tile: i0 = 4*(t>>4), j0 = 4*(t&15)
    const int i0 = (t >> 4) << 2;
    const int j0 = (t & 15) << 2;
    float acc[4][4];
    #pragma unroll
    for (int r = 0; r < 4; ++r)
        #pragma unroll
        for (int c = 0; c < 4; ++c) acc[r][c] = 0.f;

    #pragma unroll 8
    for (int d = 0; d < 64; ++d) {
        float4 av = *reinterpret_cast<const float4*>(&sAT[d * 64 + i0]);
        float4 bv = *reinterpret_cast<const float4*>(&sBT[d * 64 + j0]);
        float ar[4] = {av.x, av.y, av.z, av.w};
        float bc[4] = {bv.x, bv.y, bv.z, bv.w};
        #pragma unroll
        for (int r = 0; r < 4; ++r)
            #pragma unroll
            for (int c = 0; c < 4; ++c) {
                float df = ar[r] - bc[c];
                acc[r][c] = fmaf(df, df, acc[r][c]);
            }
    }

    unsigned uv[16];
    #pragma unroll
    for (int r = 0; r < 4; ++r)
        #pragma unroll
        for (int c = 0; c < 4; ++c) uv[r * 4 + c] = __float_as_uint(acc[r][c]);

    __syncthreads();                 // LDS reads done; smem reused as hist
    int* hist = reinterpret_cast<int*>(smem);

    bool act[16];
    #pragma unroll
    for (int x = 0; x < 16; ++x) act[x] = true;

    int need = 2047;                 // zero-based lower median of 4096
    unsigned result = 0;

    const int shifts[3] = {19, 7, 0};   // bits 30:19, 18:7, 6:0
    const int nbits [3] = {12, 12, 7};
    for (int lv = 0; lv < 3; ++lv) {
        const int      sh   = shifts[lv];
        const unsigned mask = (1u << nbits[lv]) - 1u;
        const int      NB_  = 1 << nbits[lv];

        for (int x = t; x < NB_; x += 256) hist[x] = 0;
        __syncthreads();
        #pragma unroll
        for (int x = 0; x < 16; ++x)
            if (act[x]) atomicAdd(&hist[(uv[x] >> sh) & mask], 1);
        __syncthreads();

        int lbins[16]; int lsum = 0;
        #pragma unroll
        for (int x = 0; x < 16; ++x) {
            int idx = t * 16 + x;
            int h = (idx < NB_) ? hist[idx] : 0;
            lbins[x] = h; lsum += h;
        }
        int v = lsum;
        #pragma unroll
        for (int off = 1; off < 64; off <<= 1) {
            int o = __shfl_up(v, off, 64);
            if (lane >= off) v += o;
        }
        if (lane == 63) sWave[wave] = v;
        __syncthreads();
        int woff = 0;
        for (int w2 = 0; w2 < wave; ++w2) woff += sWave[w2];
        int excl = woff + v - lsum;
        if (lsum > 0 && need >= excl && need < excl + lsum) {
            int acc2 = excl;
            #pragma unroll
            for (int x = 0; x < 16; ++x) {
                if (need < acc2 + lbins[x]) { sSel[0] = t*16 + x; sSel[1] = need - acc2; break; }
                acc2 += lbins[x];
            }
        }
        __syncthreads();
        int bin = sSel[0]; need = sSel[1];
        result |= ((unsigned)bin) << sh;
        #pragma unroll
        for (int x = 0; x < 16; ++x)
            act[x] = act[x] && (((uv[x] >> sh) & mask) == (unsigned)bin);
        __syncthreads();
    }

    if (t == 0) {
        float med   = __uint_as_float(result);       // exact sorted[2047]
        float h     = med / (2.0f * logf(64.0f + 1.0f));
        float sigma = sqrtf(h);
        float gamma = 1.0f / (1e-8f + 2.0f * sigma * sigma);
        out_gamma[p] = gamma;
        m0tab[p]     = -2.0f * gamma;
        sGamma       = gamma;
    }
    __syncthreads();

    // kappa: regs -> LDS -> plain coalesced float4 stores (L2-resident for k2)
    const float gamma = sGamma;
    float* kapS = smem;              // 4096 floats [i][j]
    #pragma unroll
    for (int r = 0; r < 4; ++r)
        #pragma unroll
        for (int c = 0; c < 4; ++c)
            kapS[(i0 + r) * 64 + (j0 + c)] = __expf(-gamma * acc[r][c]);
    __syncthreads();
    float4* kapBase = reinterpret_cast<float4*>(out_kappa + ((size_t)p << 12));
    for (int e = t; e < 1024; e += 256)
        kapBase[e] = reinterpret_cast<const float4*>(kapS)[e];
}

// ---- k2: fill-shaped streaming, two pure contiguous write streams ----
#define K2_BLOCKS 2048
#define NCHUNK    8388608            // 33554432 floats / 4 per stream

__global__ __launch_bounds__(256) void rbf_k2(
    const float* __restrict__ in1, const float* __restrict__ in2,
    const float* __restrict__ m0tab, const float* __restrict__ kappa,
    float* __restrict__ out_diff, float* __restrict__ out_kgrad)
{
    const int tid = blockIdx.x * 256 + threadIdx.x;
    const int NT  = K2_BLOCKS * 256;       // 524288 threads, 16 chunks each

    // loop 1: diff — single contiguous write stream
    for (int e = tid; e < NCHUNK; e += NT) {
        int bi  = e >> 10;                 // 1024 chunks per (b,i) row
        int rem = e & 1023;
        int j   = rem >> 4;
        int d4  = (rem & 15) << 2;
        int b   = bi >> 6;
        float4 a4 = *reinterpret_cast<const float4*>(in1 + (bi << 6) + d4);
        float4 b4 = *reinterpret_cast<const float4*>(in2 + ((size_t)b << 12) + (j << 6) + d4);
        float4 df;
        df.x = a4.x - b4.x; df.y = a4.y - b4.y;
        df.z = a4.z - b4.z; df.w = a4.w - b4.w;
        *reinterpret_cast<float4*>(out_diff + ((size_t)e << 2)) = df;
    }

    // loop 2: kappa_grad — single contiguous write stream
    for (int e = tid; e < NCHUNK; e += NT) {
        int bi  = e >> 10;
        int rem = e & 1023;
        int j   = rem >> 4;
        int d4  = (rem & 15) << 2;
        int b   = bi >> 6;
        float4 a4 = *reinterpret_cast<const float4*>(in1 + (bi << 6) + d4);
        float4 b4 = *reinterpret_cast<const float4*>(in2 + ((size_t)b << 12) + (j << 6) + d4);
        float  m  = m0tab[b] * kappa[(bi << 6) + j];
        float4 kg;
        kg.x = m * (a4.x - b4.x); kg.y = m * (a4.y - b4.y);
        kg.z = m * (a4.z - b4.z); kg.w = m * (a4.w - b4.w);
        *reinterpret_cast<float4*>(out_kgrad + ((size_t)e << 2)) = kg;
    }
}

extern "C" void kernel_launch(void* const* d_in, const int* in_sizes, int n_in,
                              void* d_out, int out_size, void* d_ws, size_t ws_size,
                              hipStream_t stream) {
    const float* in1 = (const float*)d_in[0];
    const float* in2 = (const float*)d_in[1];
    float* out = (float*)d_out;

    float* out_kappa = out;                              // 524288
    float* out_diff  = out + 524288;                     // 33554432
    float* out_gamma = out + 524288 + 33554432;          // 128
    float* out_kgrad = out_gamma + 128;                  // 33554432
    float* m0tab     = (float*)d_ws;                     // 128 floats

    rbf_k1<<<NBATCH,    256, 0, stream>>>(in1, in2, out_gamma, out_kappa, m0tab);
    rbf_k2<<<K2_BLOCKS, 256, 0, stream>>>(in1, in2, m0tab, out_kappa,
                                          out_diff, out_kgrad);
}

// Round 9
// 58.880 us; speedup vs baseline: 1.8482x; 1.8482x over previous
//
#include <hip/hip_runtime.h>

// Problem constants: B=128, N=64, D=64
// Outputs (flat): kappa [B,N,N]=524288, diff [B,N,N,D]=33554432,
//                 gamma [B,1,1,1]=128, kappa_grad [B,N,N,D]=33554432
//
//  k1 (1024 blocks): blocks 0..127: per-batch median -> gamma (+m0tab),
//                    kappa = exp(-g*d2) (plain stores, L2-resident).
//                    blocks 128..1023 (7 per batch): ALL diff rows, in2
//                    staged in LDS -> inner loop is ds_read + 1 nt store.
//  k2 (1024 blocks): ALL kappa_grad (8 rows/block), in2 + kappa staged in
//                    LDS -> inner loop is ds_read + FMA + 1 nt store.

#define NBATCH 128

typedef float f32x4 __attribute__((ext_vector_type(4)));

__device__ __forceinline__ void nt_store4(float* p, float x, float y, float z, float w) {
    f32x4 v = {x, y, z, w};
    __builtin_nontemporal_store(v, reinterpret_cast<f32x4*>(p));
}

__global__ __launch_bounds__(256) void rbf_k1(
    const float* __restrict__ in1, const float* __restrict__ in2,
    float* __restrict__ out_diff, float* __restrict__ out_gamma,
    float* __restrict__ out_kappa, float* __restrict__ m0tab)
{
    __shared__ float smem[2 * 64 * 64];   // median: A^T,B^T -> hist -> kappa
                                          // writer: in2 slice (16 KB)
    __shared__ int   sWave[4];
    __shared__ int   sSel[2];
    __shared__ float sGamma;

    const int p    = blockIdx.x;
    const int t    = threadIdx.x;
    const int wave = t >> 6;
    const int lane = t & 63;

    if (p >= NBATCH) {
        // ---------- diff writer: 7 blocks per batch, rows (w*64)/7 .. ----------
        const int wb = p - NBATCH;
        const int b  = wb / 7;
        const int w  = wb - b * 7;
        const int r0 = (w * 64) / 7;
        const int r1 = ((w + 1) * 64) / 7;

        // stage in2 batch slice (16 KB) into LDS, linear
        const float* in2b = in2 + ((size_t)b << 12);
        for (int e = t; e < 1024; e += 256) {
            float4 v = *reinterpret_cast<const float4*>(in2b + (e << 2));
            *reinterpret_cast<float4*>(&smem[e << 2]) = v;
        }
        __syncthreads();

        const int jo = lane >> 4;
        const int q  = lane & 15;
        const int d4 = q << 2;
        for (int r = r0; r < r1; ++r) {
            const int bi = (b << 6) + r;
            const float4 a4 = *reinterpret_cast<const float4*>(in1 + ((size_t)bi << 6) + d4);
            float* diffBase = out_diff + ((size_t)bi << 12);
            #pragma unroll
            for (int it = 0; it < 4; ++it) {
                int j = wave * 16 + it * 4 + jo;
                float4 b4 = *reinterpret_cast<const float4*>(&smem[(j << 6) + d4]);
                nt_store4(diffBase + (j << 6) + d4,
                          a4.x - b4.x, a4.y - b4.y, a4.z - b4.z, a4.w - b4.w);
            }
        }
        return;
    }

    // ---------- median + kappa for batch p ----------
    float* sAT = smem;            // [d][i], stride 64
    float* sBT = smem + 4096;     // [d][j], stride 64

    const float* A  = in1 + p * 4096;
    const float* Bv = in2 + p * 4096;

    for (int e = t; e < 1024; e += 256) {
        int i = e >> 4, d0 = (e & 15) << 2;
        float4 av = *reinterpret_cast<const float4*>(A  + (i << 6) + d0);
        float4 bv = *reinterpret_cast<const float4*>(Bv + (i << 6) + d0);
        sAT[(d0+0)*64 + i] = av.x; sAT[(d0+1)*64 + i] = av.y;
        sAT[(d0+2)*64 + i] = av.z; sAT[(d0+3)*64 + i] = av.w;
        sBT[(d0+0)*64 + i] = bv.x; sBT[(d0+1)*64 + i] = bv.y;
        sBT[(d0+2)*64 + i] = bv.z; sBT[(d0+3)*64 + i] = bv.w;
    }
    __syncthreads();

    // 4x4 register tile: i0 = 4*(t>>4), j0 = 4*(t&15)
    const int i0 = (t >> 4) << 2;
    const int j0 = (t & 15) << 2;
    float acc[4][4];
    #pragma unroll
    for (int r = 0; r < 4; ++r)
        #pragma unroll
        for (int c = 0; c < 4; ++c) acc[r][c] = 0.f;

    #pragma unroll 8
    for (int d = 0; d < 64; ++d) {
        float4 av = *reinterpret_cast<const float4*>(&sAT[d * 64 + i0]);
        float4 bv = *reinterpret_cast<const float4*>(&sBT[d * 64 + j0]);
        float ar[4] = {av.x, av.y, av.z, av.w};
        float bc[4] = {bv.x, bv.y, bv.z, bv.w};
        #pragma unroll
        for (int r = 0; r < 4; ++r)
            #pragma unroll
            for (int c = 0; c < 4; ++c) {
                float df = ar[r] - bc[c];
                acc[r][c] = fmaf(df, df, acc[r][c]);
            }
    }

    unsigned uv[16];
    #pragma unroll
    for (int r = 0; r < 4; ++r)
        #pragma unroll
        for (int c = 0; c < 4; ++c) uv[r * 4 + c] = __float_as_uint(acc[r][c]);

    __syncthreads();                 // LDS reads done; smem reused as hist
    int* hist = reinterpret_cast<int*>(smem);

    bool act[16];
    #pragma unroll
    for (int x = 0; x < 16; ++x) act[x] = true;

    int need = 2047;                 // zero-based lower median of 4096
    unsigned result = 0;

    const int shifts[3] = {19, 7, 0};   // bits 30:19, 18:7, 6:0
    const int nbits [3] = {12, 12, 7};
    for (int lv = 0; lv < 3; ++lv) {
        const int      sh   = shifts[lv];
        const unsigned mask = (1u << nbits[lv]) - 1u;
        const int      NB_  = 1 << nbits[lv];

        for (int x = t; x < NB_; x += 256) hist[x] = 0;
        __syncthreads();
        #pragma unroll
        for (int x = 0; x < 16; ++x)
            if (act[x]) atomicAdd(&hist[(uv[x] >> sh) & mask], 1);
        __syncthreads();

        int lbins[16]; int lsum = 0;
        #pragma unroll
        for (int x = 0; x < 16; ++x) {
            int idx = t * 16 + x;
            int h = (idx < NB_) ? hist[idx] : 0;
            lbins[x] = h; lsum += h;
        }
        int v = lsum;
        #pragma unroll
        for (int off = 1; off < 64; off <<= 1) {
            int o = __shfl_up(v, off, 64);
            if (lane >= off) v += o;
        }
        if (lane == 63) sWave[wave] = v;
        __syncthreads();
        int woff = 0;
        for (int w2 = 0; w2 < wave; ++w2) woff += sWave[w2];
        int excl = woff + v - lsum;
        if (lsum > 0 && need >= excl && need < excl + lsum) {
            int acc2 = excl;
            #pragma unroll
            for (int x = 0; x < 16; ++x) {
                if (need < acc2 + lbins[x]) { sSel[0] = t*16 + x; sSel[1] = need - acc2; break; }
                acc2 += lbins[x];
            }
        }
        __syncthreads();
        int bin = sSel[0]; need = sSel[1];
        result |= ((unsigned)bin) << sh;
        #pragma unroll
        for (int x = 0; x < 16; ++x)
            act[x] = act[x] && (((uv[x] >> sh) & mask) == (unsigned)bin);
        __syncthreads();
    }

    if (t == 0) {
        float med   = __uint_as_float(result);       // exact sorted[2047]
        float h     = med / (2.0f * logf(64.0f + 1.0f));
        float sigma = sqrtf(h);
        float gamma = 1.0f / (1e-8f + 2.0f * sigma * sigma);
        out_gamma[p] = gamma;
        m0tab[p]     = -2.0f * gamma;
        sGamma       = gamma;
    }
    __syncthreads();

    // kappa: regs -> LDS -> plain coalesced stores (stays L2-resident for k2)
    const float gamma = sGamma;
    float* kapS = smem;              // 4096 floats [i][j]
    #pragma unroll
    for (int r = 0; r < 4; ++r)
        #pragma unroll
        for (int c = 0; c < 4; ++c)
            kapS[(i0 + r) * 64 + (j0 + c)] = __expf(-gamma * acc[r][c]);
    __syncthreads();
    float4* kapBase = reinterpret_cast<float4*>(out_kappa + ((size_t)p << 12));
    for (int e = t; e < 1024; e += 256)
        kapBase[e] = reinterpret_cast<const float4*>(kapS)[e];
}

// ---- k2: kappa_grad only; in2 + kappa in LDS -> pure nt-store stream ----
__global__ __launch_bounds__(256) void rbf_k2(
    const float* __restrict__ in1, const float* __restrict__ in2,
    const float* __restrict__ m0tab, const float* __restrict__ kappa,
    float* __restrict__ out_kgrad)
{
    __shared__ float sB2[4096];      // in2 batch slice, 16 KB
    __shared__ float sKap[512];      // kappa for this block's 8 rows, 2 KB

    const int blk  = blockIdx.x;
    const int b    = blk >> 3;       // 8 blocks per batch
    const int w8   = blk & 7;        // 8 rows each
    const int t    = threadIdx.x;
    const int wave = t >> 6;
    const int lane = t & 63;
    const int jo   = lane >> 4;
    const int q    = lane & 15;
    const int d4   = q << 2;

    const float m0 = m0tab[b];
    const float* in2b = in2 + ((size_t)b << 12);
    for (int e = t; e < 1024; e += 256) {
        float4 v = *reinterpret_cast<const float4*>(in2b + (e << 2));
        *reinterpret_cast<float4*>(&sB2[e << 2]) = v;
    }
    if (t < 128) {
        float4 v = *reinterpret_cast<const float4*>(
            kappa + ((size_t)b << 12) + (w8 << 9) + (t << 2));
        *reinterpret_cast<float4*>(&sKap[t << 2]) = v;
    }
    __syncthreads();

    for (int r = 0; r < 8; ++r) {
        const int bi = (b << 6) + (w8 << 3) + r;
        const float4 a4 = *reinterpret_cast<const float4*>(in1 + ((size_t)bi << 6) + d4);
        float* kgBase = out_kgrad + ((size_t)bi << 12);
        #pragma unroll
        for (int it = 0; it < 4; ++it) {
            int j = wave * 16 + it * 4 + jo;
            float4 b4 = *reinterpret_cast<const float4*>(&sB2[(j << 6) + d4]);
            float  m  = m0 * sKap[(r << 6) + j];
            nt_store4(kgBase + (j << 6) + d4,
                      m * (a4.x - b4.x), m * (a4.y - b4.y),
                      m * (a4.z - b4.z), m * (a4.w - b4.w));
        }
    }
}

extern "C" void kernel_launch(void* const* d_in, const int* in_sizes, int n_in,
                              void* d_out, int out_size, void* d_ws, size_t ws_size,
                              hipStream_t stream) {
    const float* in1 = (const float*)d_in[0];
    const float* in2 = (const float*)d_in[1];
    float* out = (float*)d_out;

    float* out_kappa = out;                              // 524288
    float* out_diff  = out + 524288;                     // 33554432
    float* out_gamma = out + 524288 + 33554432;          // 128
    float* out_kgrad = out_gamma + 128;                  // 33554432
    float* m0tab     = (float*)d_ws;                     // 128 floats

    rbf_k1<<<NBATCH + NBATCH * 7, 256, 0, stream>>>(in1, in2, out_diff,
                                                    out_gamma, out_kappa, m0tab);
    rbf_k2<<<NBATCH * 8,          256, 0, stream>>>(in1, in2, m0tab, out_kappa,
                                                    out_kgrad);
}

// Round 10
// 54.886 us; speedup vs baseline: 1.9827x; 1.0728x over previous
//
#include <hip/hip_runtime.h>

// Problem constants: B=128, N=64, D=64
// Outputs (flat): kappa [B,N,N]=524288, diff [B,N,N,D]=33554432,
//                 gamma [B,1,1,1]=128, kappa_grad [B,N,N,D]=33554432
//
//  k1 (1024 blocks): blocks 0..127: per-batch median -> gamma (+m0tab),
//                    kappa = exp(-g*d2) (plain stores, L2-resident).
//                    blocks 128..1023 (7 per batch): ALL diff rows, in2
//                    staged in LDS -> inner loop is ds_read + 1 plain store.
//  k2 (1024 blocks): ALL kappa_grad (8 rows/block), in2 + kappa staged in
//                    LDS -> inner loop is ds_read + FMA + 1 plain store.
//
// R10 experiment: nt -> plain stores (single variable vs R9).

#define NBATCH 128

__device__ __forceinline__ void st4(float* p, float x, float y, float z, float w) {
    float4 v = make_float4(x, y, z, w);
    *reinterpret_cast<float4*>(p) = v;
}

__global__ __launch_bounds__(256) void rbf_k1(
    const float* __restrict__ in1, const float* __restrict__ in2,
    float* __restrict__ out_diff, float* __restrict__ out_gamma,
    float* __restrict__ out_kappa, float* __restrict__ m0tab)
{
    __shared__ float smem[2 * 64 * 64];   // median: A^T,B^T -> hist -> kappa
                                          // writer: in2 slice (16 KB)
    __shared__ int   sWave[4];
    __shared__ int   sSel[2];
    __shared__ float sGamma;

    const int p    = blockIdx.x;
    const int t    = threadIdx.x;
    const int wave = t >> 6;
    const int lane = t & 63;

    if (p >= NBATCH) {
        // ---------- diff writer: 7 blocks per batch ----------
        const int wb = p - NBATCH;
        const int b  = wb / 7;
        const int w  = wb - b * 7;
        const int r0 = (w * 64) / 7;
        const int r1 = ((w + 1) * 64) / 7;

        const float* in2b = in2 + ((size_t)b << 12);
        for (int e = t; e < 1024; e += 256) {
            float4 v = *reinterpret_cast<const float4*>(in2b + (e << 2));
            *reinterpret_cast<float4*>(&smem[e << 2]) = v;
        }
        __syncthreads();

        const int jo = lane >> 4;
        const int q  = lane & 15;
        const int d4 = q << 2;
        for (int r = r0; r < r1; ++r) {
            const int bi = (b << 6) + r;
            const float4 a4 = *reinterpret_cast<const float4*>(in1 + ((size_t)bi << 6) + d4);
            float* diffBase = out_diff + ((size_t)bi << 12);
            #pragma unroll
            for (int it = 0; it < 4; ++it) {
                int j = wave * 16 + it * 4 + jo;
                float4 b4 = *reinterpret_cast<const float4*>(&smem[(j << 6) + d4]);
                st4(diffBase + (j << 6) + d4,
                    a4.x - b4.x, a4.y - b4.y, a4.z - b4.z, a4.w - b4.w);
            }
        }
        return;
    }

    // ---------- median + kappa for batch p ----------
    float* sAT = smem;            // [d][i], stride 64
    float* sBT = smem + 4096;     // [d][j], stride 64

    const float* A  = in1 + p * 4096;
    const float* Bv = in2 + p * 4096;

    for (int e = t; e < 1024; e += 256) {
        int i = e >> 4, d0 = (e & 15) << 2;
        float4 av = *reinterpret_cast<const float4*>(A  + (i << 6) + d0);
        float4 bv = *reinterpret_cast<const float4*>(Bv + (i << 6) + d0);
        sAT[(d0+0)*64 + i] = av.x; sAT[(d0+1)*64 + i] = av.y;
        sAT[(d0+2)*64 + i] = av.z; sAT[(d0+3)*64 + i] = av.w;
        sBT[(d0+0)*64 + i] = bv.x; sBT[(d0+1)*64 + i] = bv.y;
        sBT[(d0+2)*64 + i] = bv.z; sBT[(d0+3)*64 + i] = bv.w;
    }
    __syncthreads();

    const int i0 = (t >> 4) << 2;
    const int j0 = (t & 15) << 2;
    float acc[4][4];
    #pragma unroll
    for (int r = 0; r < 4; ++r)
        #pragma unroll
        for (int c = 0; c < 4; ++c) acc[r][c] = 0.f;

    #pragma unroll 8
    for (int d = 0; d < 64; ++d) {
        float4 av = *reinterpret_cast<const float4*>(&sAT[d * 64 + i0]);
        float4 bv = *reinterpret_cast<const float4*>(&sBT[d * 64 + j0]);
        float ar[4] = {av.x, av.y, av.z, av.w};
        float bc[4] = {bv.x, bv.y, bv.z, bv.w};
        #pragma unroll
        for (int r = 0; r < 4; ++r)
            #pragma unroll
            for (int c = 0; c < 4; ++c) {
                float df = ar[r] - bc[c];
                acc[r][c] = fmaf(df, df, acc[r][c]);
            }
    }

    unsigned uv[16];
    #pragma unroll
    for (int r = 0; r < 4; ++r)
        #pragma unroll
        for (int c = 0; c < 4; ++c) uv[r * 4 + c] = __float_as_uint(acc[r][c]);

    __syncthreads();                 // LDS reads done; smem reused as hist
    int* hist = reinterpret_cast<int*>(smem);

    bool act[16];
    #pragma unroll
    for (int x = 0; x < 16; ++x) act[x] = true;

    int need = 2047;                 // zero-based lower median of 4096
    unsigned result = 0;

    const int shifts[3] = {19, 7, 0};   // bits 30:19, 18:7, 6:0
    const int nbits [3] = {12, 12, 7};
    for (int lv = 0; lv < 3; ++lv) {
        const int      sh   = shifts[lv];
        const unsigned mask = (1u << nbits[lv]) - 1u;
        const int      NB_  = 1 << nbits[lv];

        for (int x = t; x < NB_; x += 256) hist[x] = 0;
        __syncthreads();
        #pragma unroll
        for (int x = 0; x < 16; ++x)
            if (act[x]) atomicAdd(&hist[(uv[x] >> sh) & mask], 1);
        __syncthreads();

        int lbins[16]; int lsum = 0;
        #pragma unroll
        for (int x = 0; x < 16; ++x) {
            int idx = t * 16 + x;
            int h = (idx < NB_) ? hist[idx] : 0;
            lbins[x] = h; lsum += h;
        }
        int v = lsum;
        #pragma unroll
        for (int off = 1; off < 64; off <<= 1) {
            int o = __shfl_up(v, off, 64);
            if (lane >= off) v += o;
        }
        if (lane == 63) sWave[wave] = v;
        __syncthreads();
        int woff = 0;
        for (int w2 = 0; w2 < wave; ++w2) woff += sWave[w2];
        int excl = woff + v - lsum;
        if (lsum > 0 && need >= excl && need < excl + lsum) {
            int acc2 = excl;
            #pragma unroll
            for (int x = 0; x < 16; ++x) {
                if (need < acc2 + lbins[x]) { sSel[0] = t*16 + x; sSel[1] = need - acc2; break; }
                acc2 += lbins[x];
            }
        }
        __syncthreads();
        int bin = sSel[0]; need = sSel[1];
        result |= ((unsigned)bin) << sh;
        #pragma unroll
        for (int x = 0; x < 16; ++x)
            act[x] = act[x] && (((uv[x] >> sh) & mask) == (unsigned)bin);
        __syncthreads();
    }

    if (t == 0) {
        float med   = __uint_as_float(result);       // exact sorted[2047]
        float h     = med / (2.0f * logf(64.0f + 1.0f));
        float sigma = sqrtf(h);
        float gamma = 1.0f / (1e-8f + 2.0f * sigma * sigma);
        out_gamma[p] = gamma;
        m0tab[p]     = -2.0f * gamma;
        sGamma       = gamma;
    }
    __syncthreads();

    // kappa: regs -> LDS -> plain coalesced stores (stays L2-resident for k2)
    const float gamma = sGamma;
    float* kapS = smem;              // 4096 floats [i][j]
    #pragma unroll
    for (int r = 0; r < 4; ++r)
        #pragma unroll
        for (int c = 0; c < 4; ++c)
            kapS[(i0 + r) * 64 + (j0 + c)] = __expf(-gamma * acc[r][c]);
    __syncthreads();
    float4* kapBase = reinterpret_cast<float4*>(out_kappa + ((size_t)p << 12));
    for (int e = t; e < 1024; e += 256)
        kapBase[e] = reinterpret_cast<const float4*>(kapS)[e];
}

// ---- k2: kappa_grad only; in2 + kappa in LDS -> pure store stream ----
__global__ __launch_bounds__(256) void rbf_k2(
    const float* __restrict__ in1, const float* __restrict__ in2,
    const float* __restrict__ m0tab, const float* __restrict__ kappa,
    float* __restrict__ out_kgrad)
{
    __shared__ float sB2[4096];      // in2 batch slice, 16 KB
    __shared__ float sKap[512];      // kappa for this block's 8 rows, 2 KB

    const int blk  = blockIdx.x;
    const int b    = blk >> 3;       // 8 blocks per batch
    const int w8   = blk & 7;        // 8 rows each
    const int t    = threadIdx.x;
    const int wave = t >> 6;
    const int lane = t & 63;
    const int jo   = lane >> 4;
    const int q    = lane & 15;
    const int d4   = q << 2;

    const float m0 = m0tab[b];
    const float* in2b = in2 + ((size_t)b << 12);
    for (int e = t; e < 1024; e += 256) {
        float4 v = *reinterpret_cast<const float4*>(in2b + (e << 2));
        *reinterpret_cast<float4*>(&sB2[e << 2]) = v;
    }
    if (t < 128) {
        float4 v = *reinterpret_cast<const float4*>(
            kappa + ((size_t)b << 12) + (w8 << 9) + (t << 2));
        *reinterpret_cast<float4*>(&sKap[t << 2]) = v;
    }
    __syncthreads();

    for (int r = 0; r < 8; ++r) {
        const int bi = (b << 6) + (w8 << 3) + r;
        const float4 a4 = *reinterpret_cast<const float4*>(in1 + ((size_t)bi << 6) + d4);
        float* kgBase = out_kgrad + ((size_t)bi << 12);
        #pragma unroll
        for (int it = 0; it < 4; ++it) {
            int j = wave * 16 + it * 4 + jo;
            float4 b4 = *reinterpret_cast<const float4*>(&sB2[(j << 6) + d4]);
            float  m  = m0 * sKap[(r << 6) + j];
            st4(kgBase + (j << 6) + d4,
                m * (a4.x - b4.x), m * (a4.y - b4.y),
                m * (a4.z - b4.z), m * (a4.w - b4.w));
        }
    }
}

extern "C" void kernel_launch(void* const* d_in, const int* in_sizes, int n_in,
                              void* d_out, int out_size, void* d_ws, size_t ws_size,
                              hipStream_t stream) {
    const float* in1 = (const float*)d_in[0];
    const float* in2 = (const float*)d_in[1];
    float* out = (float*)d_out;

    float* out_kappa = out;                              // 524288
    float* out_diff  = out + 524288;                     // 33554432
    float* out_gamma = out + 524288 + 33554432;          // 128
    float* out_kgrad = out_gamma + 128;                  // 33554432
    float* m0tab     = (float*)d_ws;                     // 128 floats

    rbf_k1<<<NBATCH + NBATCH * 7, 256, 0, stream>>>(in1, in2, out_diff,
                                                    out_gamma, out_kappa, m0tab);
    rbf_k2<<<NBATCH * 8,          256, 0, stream>>>(in1, in2, m0tab, out_kappa,
                                                    out_kgrad);
}